// Round 7
// baseline (232.544 us; speedup 1.0000x reference)
//
#include <hip/hip_runtime.h>
#include <hip/hip_bf16.h>

#define AS1 __attribute__((address_space(1)))
#define AS3 __attribute__((address_space(3)))

typedef unsigned short u16;
typedef short bf16x8 __attribute__((ext_vector_type(8)));
typedef unsigned short u16x8 __attribute__((ext_vector_type(8)));
typedef float f32x4 __attribute__((ext_vector_type(4)));
typedef float f32x16 __attribute__((ext_vector_type(16)));

#define MFMA16 __builtin_amdgcn_mfma_f32_16x16x32_bf16
#define MFMA32 __builtin_amdgcn_mfma_f32_32x32x16_bf16

// ---------------- helpers ----------------

__device__ __forceinline__ u16 f2bf(float f) {        // RNE (finite data)
  union { float f; unsigned u; } c; c.f = f;
  unsigned u = c.u;
  u = u + 0x7fffu + ((u >> 16) & 1u);
  return (u16)(u >> 16);
}

__device__ __forceinline__ float fexp2(float x) {
#if __has_builtin(__builtin_amdgcn_exp2f)
  return __builtin_amdgcn_exp2f(x);
#else
  return exp2f(x);
#endif
}

// pack bf16(a) low16, bf16(b) high16 (truncating) — 1 v_perm_b32
__device__ __forceinline__ unsigned pack_bf(float a, float b) {
  union { float f; unsigned u; } ua, ub; ua.f = a; ub.f = b;
  return __builtin_amdgcn_perm(ub.u, ua.u, 0x07060302u);
}

__device__ __forceinline__ void gl_lds16(const void* g, void* l) {
  __builtin_amdgcn_global_load_lds((const AS1 void*)g, (AS3 void*)l, 16, 0, 0);
}

// ---------------- cast fp32 -> bf16, with 64-col-tile granule swizzle ----------------

__global__ void cast_all_kernel(const float* __restrict__ x,
                                const float* __restrict__ wqkv,
                                const float* __restrict__ wout,
                                u16* __restrict__ ws) {
  int i = blockIdx.x * blockDim.x + threadIdx.x;   // float4 index, 3145728 total
  const float4* src;
  int rel;
  size_t matbase;
  if (i < 2097152)      { src = (const float4*)x + i;                rel = i;           matbase = 0; }
  else if (i < 2883584) { src = (const float4*)wqkv + (i - 2097152); rel = i - 2097152; matbase = 8388608; }
  else                  { src = (const float4*)wout + (i - 2883584); rel = i - 2883584; matbase = 11534336; }
  float4 f = *src;
  ushort4 o;
  o.x = f2bf(f.x); o.y = f2bf(f.y); o.z = f2bf(f.z); o.w = f2bf(f.w);
  int fe  = rel * 4;
  int row = fe >> 10, c = fe & 1023;
  int newc = (c & ~63) | (((((c >> 3) ^ row) & 7) << 3)) | (c & 7);
  ((ushort4*)ws)[(matbase + (size_t)row * 1024 + newc) >> 2] = o;
}

// ---------------- GEMM: C[M,N] = A[M,K] * B[N,K]^T  (bf16 in, fp32 acc) ----------------
// r7: 32x32x16 MFMA (same staging/swizzle/structure). Per K-tile: 16 ds_read_b128 +
// 16 MFMA32 (was 16 + 32 MFMA16) -> ~17% fewer matrix-pipe cycles, half the issue slots.
// Frag layouts (HW-verified, learn_hip m74/m101): A/B: row=lane&31, k=(lane>>5)*8+j;
// C/D: col=lane&31, row=(reg&3)+8*(reg>>2)+4*(lane>>5).
// EPI==1: QKV epilogue; V-part blocks (bn>=2048) write V in attn operand order
// (h2=i, q2=rq, ssb=4*hi+(reg&3) -> packed 8B stores).

template<int EPI>
__global__ __launch_bounds__(256) void gemm_bt(
    const u16* __restrict__ A, const u16* __restrict__ Bm,
    float* __restrict__ Cf,
    u16* __restrict__ qd, u16* __restrict__ kd, u16* __restrict__ vd,
    int M, int N, int K)
{
  __shared__ u16 As[128 * 64];
  __shared__ u16 Bs[128 * 64];

  const int tid  = threadIdx.x;
  const int wave = tid >> 6, lane = tid & 63;
  const int l32 = lane & 31, hi5 = lane >> 5;
  const int bm = blockIdx.y * 128, bn = blockIdx.x * 128;
  const int wm = (wave >> 1) * 64, wn = (wave & 1) * 64;

  f32x16 acc[2][2] = {};

  const int srow = wave * 32 + (lane >> 3);
  const int scol = (lane & 7) * 8;

  for (int kt = 0; kt < K; kt += 64) {
    __syncthreads();
    #pragma unroll
    for (int i = 0; i < 4; ++i) {
      gl_lds16(&A[(size_t)(bm + srow + i * 8) * K + kt + scol], &As[(wave * 32 + i * 8) * 64]);
      gl_lds16(&Bm[(size_t)(bn + srow + i * 8) * K + kt + scol], &Bs[(wave * 32 + i * 8) * 64]);
    }
    __syncthreads();
    #pragma unroll
    for (int kk = 0; kk < 64; kk += 16) {
      const int kg = (kk >> 3) + hi5;
      bf16x8 af[2], bb[2];
      #pragma unroll
      for (int i = 0; i < 2; ++i) {
        int row = wm + i * 32 + l32;
        af[i] = *(const bf16x8*)&As[row * 64 + (((kg ^ row) & 7) << 3)];
      }
      #pragma unroll
      for (int j = 0; j < 2; ++j) {
        int row = wn + j * 32 + l32;
        bb[j] = *(const bf16x8*)&Bs[row * 64 + (((kg ^ row) & 7) << 3)];
      }
      #pragma unroll
      for (int i = 0; i < 2; ++i)
        #pragma unroll
        for (int j = 0; j < 2; ++j)
          acc[i][j] = MFMA32(af[i], bb[j], acc[i][j], 0, 0, 0);
    }
  }

  const int partU = bn >> 10;          // block-uniform (128 | 1024)
  if (EPI == 1 && partU == 2) {
    // ---- fused pack_v: write V straight into operand-order vt ----
    const int b = bm >> 12;
    const int t = ((bm + wm) & 4095) >> 6;        // uniform: (bm+wm)%64==0, offsets<64
    #pragma unroll
    for (int i = 0; i < 2; ++i) {                  // h2 = i (k6 = i*32 + <32>)
      #pragma unroll
      for (int j = 0; j < 2; ++j) {
        int nb  = bn + wn + j * 32;
        int h   = ((nb + l32) >> 6) & 15;          // uniform over l32 (nb%32==0)
        int jd  = ((nb & 63) + l32) >> 4;
        int d15 = l32 & 15;
        #pragma unroll
        for (int rq = 0; rq < 4; ++rq) {           // q2 = rq; k6 = i*32+8*rq+4*hi5+rr
          unsigned lo = (unsigned)f2bf(acc[i][j][rq * 4 + 0]) |
                        ((unsigned)f2bf(acc[i][j][rq * 4 + 1]) << 16);
          unsigned hh = (unsigned)f2bf(acc[i][j][rq * 4 + 2]) |
                        ((unsigned)f2bf(acc[i][j][rq * 4 + 3]) << 16);
          uint2 w; w.x = lo; w.y = hh;
          *(uint2*)&vd[(((size_t)(b * 16 + h)) << 18) + (size_t)t * 4096
                       + jd * 1024 + i * 512 + (rq * 16 + d15) * 8 + hi5 * 4] = w;
        }
      }
    }
  } else {
    #pragma unroll
    for (int i = 0; i < 2; ++i) {
      #pragma unroll
      for (int j = 0; j < 2; ++j) {
        int n = bn + wn + j * 32 + l32;
        #pragma unroll
        for (int reg = 0; reg < 16; ++reg) {
          int m = bm + wm + i * 32 + (reg & 3) + 8 * (reg >> 2) + 4 * hi5;
          float val = acc[i][j][reg];
          if (EPI == 0) {
            Cf[(size_t)m * N + n] = val;
          } else {
            int part = n >> 10, rem = n & 1023;
            int h = rem >> 6, d = rem & 63;
            int b = m >> 12, s = m & 4095;
            if (part == 0) val *= 0.1803368801111244f;   // 0.125 * log2(e), exp2 path
            u16* dst = (part == 0) ? qd : kd;            // part 2 handled above
            dst[((size_t)((b * 16 + h) * 4096 + s)) * 64 + d] = f2bf(val);
          }
        }
      }
    }
  }
}

// ---------------- attention: 64 queries/wave, 4 waves/block, S^T trick, coalesced V ------
// (r6-proven: PSTR=68 padding, V loads inside PV h-loop, setprio around MFMA clusters.)

#define PSTR 68

__global__ __launch_bounds__(256, 2) void attn_kernel(
    const u16* __restrict__ qb, const u16* __restrict__ kb,
    const u16* __restrict__ vt, u16* __restrict__ ob)
{
  __shared__ u16 Ps[4][64 * PSTR];

  const int tid  = threadIdx.x;
  const int wave = tid >> 6;
  const int lane = tid & 63;
  const int quad = lane >> 4, l16 = lane & 15;
  const int bid  = blockIdx.x;
  const int bh   = bid & 31;
  const int t0   = (((bid >> 5) << 2) | wave) << 6;   // 64 queries per wave
  const size_t base = (size_t)bh << 18;
  u16* __restrict__ ps = &Ps[wave][0];

  const int l64 = l16 * 64 + quad * 8;
  const u16* vbase = vt + base + lane * 8;   // + tile*4096 + jd*1024 + h*512

  // Q B-fragments (B[n=query l16][k=dh]); q pre-scaled by 0.125*log2e
  const u16* qp = qb + base + (size_t)t0 * 64 + l64;
  bf16x8 bq[4][2];
  #pragma unroll
  for (int i = 0; i < 4; ++i) {
    bq[i][0] = *(const bf16x8*)(qp + i * 1024);
    bq[i][1] = *(const bf16x8*)(qp + i * 1024 + 32);
  }

  f32x4 oacc[4][4] = {};
  f32x4 lacc[4] = {};
  bf16x8 ones;
  #pragma unroll
  for (int s = 0; s < 8; ++s) ones[s] = (short)0x3F80;

  const int lo = max(0, t0 - 511) >> 6;
  const int hi = (t0 + 63) >> 6;

  auto loadK = [&](int kb0, bf16x8 (&kf)[4][2]) {
    #pragma unroll
    for (int j = 0; j < 4; ++j) {
      const u16* krow = kb + base + (size_t)(kb0 + j * 16) * 64 + l64;
      kf[j][0] = *(const bf16x8*)(krow);
      kf[j][1] = *(const bf16x8*)(krow + 32);
    }
  };

  bf16x8 ka[4][2], kb2[4][2];

  // ======== prefix tile (keys 0..15 causal; keys 16..31 zero-filled) ========
  {
    const u16* kpre = kb + base + l64;
    bf16x8 pk0 = *(const bf16x8*)(kpre);
    bf16x8 pk1 = *(const bf16x8*)(kpre + 32);
    loadK(lo << 6, ka);                        // prefetch first window tile
    bf16x8 pv[4];
    #pragma unroll
    for (int jd = 0; jd < 4; ++jd)
      pv[jd] = *(const bf16x8*)(vbase + jd * 1024);   // tile 0, h=0

    #pragma unroll
    for (int i = 0; i < 4; ++i) {
      f32x4 t4 = {};
      t4 = MFMA16(pk0, bq[i][0], t4, 0, 0, 0);
      t4 = MFMA16(pk1, bq[i][1], t4, 0, 0, 0);
      int row = i * 16 + l16;
      int qpos = t0 + row;
      float p[4];
      #pragma unroll
      for (int r = 0; r < 4; ++r) {
        int kpos = quad * 4 + r;
        p[r] = (kpos <= qpos) ? fexp2(t4[r]) : 0.f;
      }
      uint2 w;
      w.x = pack_bf(p[0], p[1]);
      w.y = pack_bf(p[2], p[3]);
      *(uint2*)&ps[row * PSTR + ((quad ^ l16) & 15) * 4] = w;
      uint2 z; z.x = 0u; z.y = 0u;
      *(uint2*)&ps[row * PSTR + (((4 + quad) ^ l16) & 15) * 4] = z;
    }
    #pragma unroll
    for (int i = 0; i < 4; ++i) {
      int row = i * 16 + l16;
      uint2 r0 = *(uint2*)&ps[row * PSTR + (((2 * quad) ^ l16) & 15) * 4];
      uint2 r1 = *(uint2*)&ps[row * PSTR + (((2 * quad + 1) ^ l16) & 15) * 4];
      union { uint4 u; bf16x8 v; } cc; cc.u = make_uint4(r0.x, r0.y, r1.x, r1.y);
      bf16x8 ap = cc.v;
      __builtin_amdgcn_s_setprio(1);
      lacc[i] = MFMA16(ap, ones, lacc[i], 0, 0, 0);
      #pragma unroll
      for (int jd = 0; jd < 4; ++jd)
        oacc[i][jd] = MFMA16(ap, pv[jd], oacc[i][jd], 0, 0, 0);
      __builtin_amdgcn_s_setprio(0);
    }
  }

  // ======== sliding-window tiles ========
  auto tilec = [&](int kb0, bf16x8 (&kf)[4][2]) {
    #pragma unroll
    for (int j = 0; j < 4; ++j) {
      const int kmin = kb0 + j * 16;
      #pragma unroll
      for (int i = 0; i < 4; ++i) {
        const int qmin = t0 + i * 16;
        const int row  = i * 16 + l16;
        uint2* dst = (uint2*)&ps[row * PSTR + (((j * 4 + quad) ^ l16) & 15) * 4];
        // wave-uniform subtile classification
        const bool sub_masked = (kmin > qmin + 15) || (qmin - kmin >= 527) || (kmin < 16);
        if (sub_masked) { uint2 z; z.x = 0u; z.y = 0u; *dst = z; continue; }
        f32x4 t4 = {};
        __builtin_amdgcn_s_setprio(1);
        t4 = MFMA16(kf[j][0], bq[i][0], t4, 0, 0, 0);
        t4 = MFMA16(kf[j][1], bq[i][1], t4, 0, 0, 0);
        __builtin_amdgcn_s_setprio(0);
        const bool sub_ok = (kmin + 15 <= qmin) && (qmin + 15 - kmin < 512);
        float p[4];
        if (sub_ok) {
          #pragma unroll
          for (int r = 0; r < 4; ++r) p[r] = fexp2(t4[r]);
        } else {
          int qpos = t0 + row;
          #pragma unroll
          for (int r = 0; r < 4; ++r) {
            int kpos = kmin + quad * 4 + r;       // kmin >= 16 guaranteed here
            unsigned diff = (unsigned)(qpos - kpos);
            p[r] = (diff < 512u) ? fexp2(t4[r]) : 0.f;
          }
        }
        uint2 w;
        w.x = pack_bf(p[0], p[1]);
        w.y = pack_bf(p[2], p[3]);
        *dst = w;
      }
    }
    // PV + l accumulation; V frags contiguous 1KB each, reused across i
    const u16* vp = vbase + (size_t)kb0 * 64;
    #pragma unroll
    for (int h = 0; h < 2; ++h) {
      bf16x8 bv0 = *(const bf16x8*)(vp + h * 512);
      bf16x8 bv1 = *(const bf16x8*)(vp + 1024 + h * 512);
      bf16x8 bv2 = *(const bf16x8*)(vp + 2048 + h * 512);
      bf16x8 bv3 = *(const bf16x8*)(vp + 3072 + h * 512);
      #pragma unroll
      for (int i = 0; i < 4; ++i) {
        int row = i * 16 + l16;
        int g0 = h * 8 + 2 * quad;
        uint2 r0 = *(uint2*)&ps[row * PSTR + ((g0 ^ l16) & 15) * 4];
        uint2 r1 = *(uint2*)&ps[row * PSTR + (((g0 + 1) ^ l16) & 15) * 4];
        union { uint4 u; bf16x8 v; } cc; cc.u = make_uint4(r0.x, r0.y, r1.x, r1.y);
        bf16x8 ap = cc.v;
        __builtin_amdgcn_s_setprio(1);
        lacc[i] = MFMA16(ap, ones, lacc[i], 0, 0, 0);
        oacc[i][0] = MFMA16(ap, bv0, oacc[i][0], 0, 0, 0);
        oacc[i][1] = MFMA16(ap, bv1, oacc[i][1], 0, 0, 0);
        oacc[i][2] = MFMA16(ap, bv2, oacc[i][2], 0, 0, 0);
        oacc[i][3] = MFMA16(ap, bv3, oacc[i][3], 0, 0, 0);
        __builtin_amdgcn_s_setprio(0);
      }
    }
  };

  for (int t = lo; t <= hi; t += 2) {
    if (t + 1 <= hi) loadK((t + 1) << 6, kb2);
    tilec(t << 6, ka);
    if (t + 1 <= hi) {
      if (t + 2 <= hi) loadK((t + 2) << 6, ka);
      tilec((t + 1) << 6, kb2);
    }
  }

  // ---- epilogue: O/l -> bf16 [B,S,H*64], granule-swizzled for GEMM3 staging ----
  const int b = bh >> 4, h = bh & 15;
  #pragma unroll
  for (int i = 0; i < 4; ++i) {
    #pragma unroll
    for (int r = 0; r < 4; ++r) {
      float inv = 1.f / lacc[i][r];
      int srow = t0 + i * 16 + quad * 4 + r;
      size_t rowoff = ((size_t)(b * 4096 + srow)) * 1024 + h * 64;
      #pragma unroll
      for (int jd = 0; jd < 4; ++jd) {
        int g = ((jd * 2 + (l16 >> 3)) ^ srow) & 7;
        ob[rowoff + (g << 3) + (l16 & 7)] = f2bf(oacc[i][jd][r] * inv);
      }
    }
  }
}

// ---------------- launch ----------------

extern "C" void kernel_launch(void* const* d_in, const int* in_sizes, int n_in,
                              void* d_out, int out_size, void* d_ws, size_t ws_size,
                              hipStream_t stream) {
  const float* x    = (const float*)d_in[0];
  const float* wqkv = (const float*)d_in[1];
  const float* wout = (const float*)d_in[2];
  float* out = (float*)d_out;

  u16* ws    = (u16*)d_ws;
  u16* xb    = ws;                                   // 8192*1024  (reused as obuf)
  u16* wqkvb = xb + (size_t)8192 * 1024;             // 3072*1024
  u16* woutb = wqkvb + (size_t)3072 * 1024;          // 1024*1024
  u16* qbuf  = woutb + (size_t)1024 * 1024;          // [2,16,4096,64]
  u16* kbuf  = qbuf + (size_t)8388608;
  u16* vbuf  = kbuf + (size_t)8388608;               // (unused now)
  u16* vtb   = vbuf + (size_t)8388608;               // operand-order V (written by gemm1)
  u16* obuf  = xb;                                   // alias: xb dead after gemm1

  cast_all_kernel<<<12288, 256, 0, stream>>>(x, wqkv, wout, ws);

  gemm_bt<1><<<dim3(24, 64), 256, 0, stream>>>(xb, wqkvb, nullptr, qbuf, kbuf, vtb,
                                               8192, 3072, 1024);
  attn_kernel<<<512, 256, 0, stream>>>(qbuf, kbuf, vtb, obuf);
  gemm_bt<0><<<dim3(8, 64), 256, 0, stream>>>(obuf, woutb, out, nullptr, nullptr, nullptr,
                                              8192, 1024, 1024);
}

// Round 8
// 219.401 us; speedup vs baseline: 1.0599x; 1.0599x over previous
//
#include <hip/hip_runtime.h>
#include <hip/hip_bf16.h>

#define AS1 __attribute__((address_space(1)))
#define AS3 __attribute__((address_space(3)))

typedef unsigned short u16;
typedef short bf16x8 __attribute__((ext_vector_type(8)));
typedef unsigned short u16x8 __attribute__((ext_vector_type(8)));
typedef float f32x4 __attribute__((ext_vector_type(4)));

#define MFMA16 __builtin_amdgcn_mfma_f32_16x16x32_bf16

// ---------------- helpers ----------------

__device__ __forceinline__ u16 f2bf(float f) {        // RNE (finite data)
  union { float f; unsigned u; } c; c.f = f;
  unsigned u = c.u;
  u = u + 0x7fffu + ((u >> 16) & 1u);
  return (u16)(u >> 16);
}

__device__ __forceinline__ float fexp2(float x) {
#if __has_builtin(__builtin_amdgcn_exp2f)
  return __builtin_amdgcn_exp2f(x);
#else
  return exp2f(x);
#endif
}

// pack bf16(a) low16, bf16(b) high16 (truncating) — 1 v_perm_b32
__device__ __forceinline__ unsigned pack_bf(float a, float b) {
  union { float f; unsigned u; } ua, ub; ua.f = a; ub.f = b;
  return __builtin_amdgcn_perm(ub.u, ua.u, 0x07060302u);
}

__device__ __forceinline__ void gl_lds16(const void* g, void* l) {
  __builtin_amdgcn_global_load_lds((const AS1 void*)g, (AS3 void*)l, 16, 0, 0);
}

// ---------------- cast fp32 -> bf16, with 64-col-tile granule swizzle ----------------

__global__ void cast_all_kernel(const float* __restrict__ x,
                                const float* __restrict__ wqkv,
                                const float* __restrict__ wout,
                                u16* __restrict__ ws) {
  int i = blockIdx.x * blockDim.x + threadIdx.x;   // float4 index, 3145728 total
  const float4* src;
  int rel;
  size_t matbase;
  if (i < 2097152)      { src = (const float4*)x + i;                rel = i;           matbase = 0; }
  else if (i < 2883584) { src = (const float4*)wqkv + (i - 2097152); rel = i - 2097152; matbase = 8388608; }
  else                  { src = (const float4*)wout + (i - 2883584); rel = i - 2883584; matbase = 11534336; }
  float4 f = *src;
  ushort4 o;
  o.x = f2bf(f.x); o.y = f2bf(f.y); o.z = f2bf(f.z); o.w = f2bf(f.w);
  int fe  = rel * 4;
  int row = fe >> 10, c = fe & 1023;
  int newc = (c & ~63) | (((((c >> 3) ^ row) & 7) << 3)) | (c & 7);
  ((ushort4*)ws)[(matbase + (size_t)row * 1024 + newc) >> 2] = o;
}

// ---------------- GEMM: C[M,N] = A[M,K] * B[N,K]^T  (bf16 in, fp32 acc) ----------------
// r6-proven 16x16x32 version (r7's 32x32 regressed: 32-row frag span defeats the 3-bit
// XOR granule perm -> 4-way LDS conflicts, 6.3M/dispatch). EPI==1: QKV epilogue; V-part
// blocks (bn>=2048) write V directly in attn operand order (pack_v fused away).

template<int EPI>
__global__ __launch_bounds__(256) void gemm_bt(
    const u16* __restrict__ A, const u16* __restrict__ Bm,
    float* __restrict__ Cf,
    u16* __restrict__ qd, u16* __restrict__ kd, u16* __restrict__ vd,
    int M, int N, int K)
{
  __shared__ u16 As[128 * 64];
  __shared__ u16 Bs[128 * 64];

  const int tid  = threadIdx.x;
  const int wave = tid >> 6, lane = tid & 63;
  const int quad = lane >> 4, l16 = lane & 15;
  const int bm = blockIdx.y * 128, bn = blockIdx.x * 128;
  const int wm = (wave >> 1) * 64, wn = (wave & 1) * 64;

  f32x4 acc[4][4] = {};

  const int srow = wave * 32 + (lane >> 3);
  const int scol = (lane & 7) * 8;

  for (int kt = 0; kt < K; kt += 64) {
    __syncthreads();
    #pragma unroll
    for (int i = 0; i < 4; ++i) {
      gl_lds16(&A[(size_t)(bm + srow + i * 8) * K + kt + scol], &As[(wave * 32 + i * 8) * 64]);
      gl_lds16(&Bm[(size_t)(bn + srow + i * 8) * K + kt + scol], &Bs[(wave * 32 + i * 8) * 64]);
    }
    __syncthreads();
    #pragma unroll
    for (int kk = 0; kk < 64; kk += 32) {
      bf16x8 af[4], bb[4];
      #pragma unroll
      for (int i = 0; i < 4; ++i) {
        int row = wm + i * 16 + l16;
        af[i] = *(const bf16x8*)&As[row * 64 + (((((kk >> 3) + quad) ^ row) & 7) << 3)];
      }
      #pragma unroll
      for (int j = 0; j < 4; ++j) {
        int row = wn + j * 16 + l16;
        bb[j] = *(const bf16x8*)&Bs[row * 64 + (((((kk >> 3) + quad) ^ row) & 7) << 3)];
      }
      #pragma unroll
      for (int i = 0; i < 4; ++i)
        #pragma unroll
        for (int j = 0; j < 4; ++j)
          acc[i][j] = MFMA16(af[i], bb[j], acc[i][j], 0, 0, 0);
    }
  }

  const int partU = bn >> 10;          // block-uniform (128 | 1024)
  if (EPI == 1 && partU == 2) {
    // ---- fused pack_v: write V straight into operand-order vt ----
    const int b = bm >> 12;
    #pragma unroll
    for (int i = 0; i < 4; ++i) {
      int s0q = (bm + wm + i * 16 + quad * 4) & 4095;
      int t  = s0q >> 6, k6 = s0q & 63;
      int h2 = k6 >> 5, q2 = (k6 >> 3) & 3, ssb = k6 & 7;
      #pragma unroll
      for (int j = 0; j < 4; ++j) {
        int nbase = bn + wn + j * 16;
        int h  = (nbase >> 6) & 15;
        int jd = (nbase & 63) >> 4;
        unsigned lo = (unsigned)f2bf(acc[i][j][0]) | ((unsigned)f2bf(acc[i][j][1]) << 16);
        unsigned hi = (unsigned)f2bf(acc[i][j][2]) | ((unsigned)f2bf(acc[i][j][3]) << 16);
        uint2 w; w.x = lo; w.y = hi;
        *(uint2*)&vd[(((size_t)(b * 16 + h)) << 18) + (size_t)t * 4096
                     + jd * 1024 + h2 * 512 + (q2 * 16 + l16) * 8 + ssb] = w;
      }
    }
  } else {
    #pragma unroll
    for (int i = 0; i < 4; ++i) {
      #pragma unroll
      for (int j = 0; j < 4; ++j) {
        #pragma unroll
        for (int r = 0; r < 4; ++r) {
          int m = bm + wm + i * 16 + quad * 4 + r;
          int n = bn + wn + j * 16 + l16;
          float val = acc[i][j][r];
          if (EPI == 0) {
            Cf[(size_t)m * N + n] = val;
          } else {
            int part = n >> 10, rem = n & 1023;
            int h = rem >> 6, d = rem & 63;
            int b = m >> 12, s = m & 4095;
            if (part == 0) val *= 0.1803368801111244f;   // 0.125 * log2(e), exp2 path
            u16* dst = (part == 0) ? qd : kd;            // part 2 handled above
            dst[((size_t)((b * 16 + h) * 4096 + s)) * 64 + d] = f2bf(val);
          }
        }
      }
    }
  }
}

// ---------------- attention: 64 queries/wave, 4 waves/block, S^T trick, coalesced V ------
// r8 single variable vs r6: load-balanced t0 remap. Old mapping gave block q the
// contiguous quartet t0/64 = {4q..4q+3}; work/wave scales ~1..10 tile-visits with t0, so
// block totals ranged ~10..40 and the heaviest blocks dispatched LAST (makespan tail).
// New: t0/64 = q + 16*((wave+q)&3) — each block holds one wave per work quartile
// (uniform block runtime), and the +q rotation spreads the heavy wave across SIMDs.
// Bijective per (b,h); all addressing derives from t0 -> correctness unchanged.

#define PSTR 68

__global__ __launch_bounds__(256, 2) void attn_kernel(
    const u16* __restrict__ qb, const u16* __restrict__ kb,
    const u16* __restrict__ vt, u16* __restrict__ ob)
{
  __shared__ u16 Ps[4][64 * PSTR];

  const int tid  = threadIdx.x;
  const int wave = tid >> 6;
  const int lane = tid & 63;
  const int quad = lane >> 4, l16 = lane & 15;
  const int bid  = blockIdx.x;
  const int bh   = bid & 31;
  const int q15  = bid >> 5;                           // 0..15
  const int wq   = (wave + q15) & 3;                   // heavy-wave SIMD rotation
  const int t0   = (q15 + 16 * wq) << 6;               // 64 queries per wave
  const size_t base = (size_t)bh << 18;
  u16* __restrict__ ps = &Ps[wave][0];

  const int l64 = l16 * 64 + quad * 8;
  const u16* vbase = vt + base + lane * 8;   // + tile*4096 + jd*1024 + h*512

  // Q B-fragments (B[n=query l16][k=dh]); q pre-scaled by 0.125*log2e
  const u16* qp = qb + base + (size_t)t0 * 64 + l64;
  bf16x8 bq[4][2];
  #pragma unroll
  for (int i = 0; i < 4; ++i) {
    bq[i][0] = *(const bf16x8*)(qp + i * 1024);
    bq[i][1] = *(const bf16x8*)(qp + i * 1024 + 32);
  }

  f32x4 oacc[4][4] = {};
  f32x4 lacc[4] = {};
  bf16x8 ones;
  #pragma unroll
  for (int s = 0; s < 8; ++s) ones[s] = (short)0x3F80;

  const int lo = max(0, t0 - 511) >> 6;
  const int hi = (t0 + 63) >> 6;

  auto loadK = [&](int kb0, bf16x8 (&kf)[4][2]) {
    #pragma unroll
    for (int j = 0; j < 4; ++j) {
      const u16* krow = kb + base + (size_t)(kb0 + j * 16) * 64 + l64;
      kf[j][0] = *(const bf16x8*)(krow);
      kf[j][1] = *(const bf16x8*)(krow + 32);
    }
  };

  bf16x8 ka[4][2], kb2[4][2];

  // ======== prefix tile (keys 0..15 causal; keys 16..31 zero-filled) ========
  {
    const u16* kpre = kb + base + l64;
    bf16x8 pk0 = *(const bf16x8*)(kpre);
    bf16x8 pk1 = *(const bf16x8*)(kpre + 32);
    loadK(lo << 6, ka);                        // prefetch first window tile
    bf16x8 pv[4];
    #pragma unroll
    for (int jd = 0; jd < 4; ++jd)
      pv[jd] = *(const bf16x8*)(vbase + jd * 1024);   // tile 0, h=0

    #pragma unroll
    for (int i = 0; i < 4; ++i) {
      f32x4 t4 = {};
      t4 = MFMA16(pk0, bq[i][0], t4, 0, 0, 0);
      t4 = MFMA16(pk1, bq[i][1], t4, 0, 0, 0);
      int row = i * 16 + l16;
      int qpos = t0 + row;
      float p[4];
      #pragma unroll
      for (int r = 0; r < 4; ++r) {
        int kpos = quad * 4 + r;
        p[r] = (kpos <= qpos) ? fexp2(t4[r]) : 0.f;
      }
      uint2 w;
      w.x = pack_bf(p[0], p[1]);
      w.y = pack_bf(p[2], p[3]);
      *(uint2*)&ps[row * PSTR + ((quad ^ l16) & 15) * 4] = w;
      uint2 z; z.x = 0u; z.y = 0u;
      *(uint2*)&ps[row * PSTR + (((4 + quad) ^ l16) & 15) * 4] = z;
    }
    #pragma unroll
    for (int i = 0; i < 4; ++i) {
      int row = i * 16 + l16;
      uint2 r0 = *(uint2*)&ps[row * PSTR + (((2 * quad) ^ l16) & 15) * 4];
      uint2 r1 = *(uint2*)&ps[row * PSTR + (((2 * quad + 1) ^ l16) & 15) * 4];
      union { uint4 u; bf16x8 v; } cc; cc.u = make_uint4(r0.x, r0.y, r1.x, r1.y);
      bf16x8 ap = cc.v;
      __builtin_amdgcn_s_setprio(1);
      lacc[i] = MFMA16(ap, ones, lacc[i], 0, 0, 0);
      #pragma unroll
      for (int jd = 0; jd < 4; ++jd)
        oacc[i][jd] = MFMA16(ap, pv[jd], oacc[i][jd], 0, 0, 0);
      __builtin_amdgcn_s_setprio(0);
    }
  }

  // ======== sliding-window tiles ========
  auto tilec = [&](int kb0, bf16x8 (&kf)[4][2]) {
    #pragma unroll
    for (int j = 0; j < 4; ++j) {
      const int kmin = kb0 + j * 16;
      #pragma unroll
      for (int i = 0; i < 4; ++i) {
        const int qmin = t0 + i * 16;
        const int row  = i * 16 + l16;
        uint2* dst = (uint2*)&ps[row * PSTR + (((j * 4 + quad) ^ l16) & 15) * 4];
        // wave-uniform subtile classification
        const bool sub_masked = (kmin > qmin + 15) || (qmin - kmin >= 527) || (kmin < 16);
        if (sub_masked) { uint2 z; z.x = 0u; z.y = 0u; *dst = z; continue; }
        f32x4 t4 = {};
        __builtin_amdgcn_s_setprio(1);
        t4 = MFMA16(kf[j][0], bq[i][0], t4, 0, 0, 0);
        t4 = MFMA16(kf[j][1], bq[i][1], t4, 0, 0, 0);
        __builtin_amdgcn_s_setprio(0);
        const bool sub_ok = (kmin + 15 <= qmin) && (qmin + 15 - kmin < 512);
        float p[4];
        if (sub_ok) {
          #pragma unroll
          for (int r = 0; r < 4; ++r) p[r] = fexp2(t4[r]);
        } else {
          int qpos = t0 + row;
          #pragma unroll
          for (int r = 0; r < 4; ++r) {
            int kpos = kmin + quad * 4 + r;       // kmin >= 16 guaranteed here
            unsigned diff = (unsigned)(qpos - kpos);
            p[r] = (diff < 512u) ? fexp2(t4[r]) : 0.f;
          }
        }
        uint2 w;
        w.x = pack_bf(p[0], p[1]);
        w.y = pack_bf(p[2], p[3]);
        *dst = w;
      }
    }
    // PV + l accumulation; V frags contiguous 1KB each, reused across i
    const u16* vp = vbase + (size_t)kb0 * 64;
    #pragma unroll
    for (int h = 0; h < 2; ++h) {
      bf16x8 bv0 = *(const bf16x8*)(vp + h * 512);
      bf16x8 bv1 = *(const bf16x8*)(vp + 1024 + h * 512);
      bf16x8 bv2 = *(const bf16x8*)(vp + 2048 + h * 512);
      bf16x8 bv3 = *(const bf16x8*)(vp + 3072 + h * 512);
      #pragma unroll
      for (int i = 0; i < 4; ++i) {
        int row = i * 16 + l16;
        int g0 = h * 8 + 2 * quad;
        uint2 r0 = *(uint2*)&ps[row * PSTR + ((g0 ^ l16) & 15) * 4];
        uint2 r1 = *(uint2*)&ps[row * PSTR + (((g0 + 1) ^ l16) & 15) * 4];
        union { uint4 u; bf16x8 v; } cc; cc.u = make_uint4(r0.x, r0.y, r1.x, r1.y);
        bf16x8 ap = cc.v;
        __builtin_amdgcn_s_setprio(1);
        lacc[i] = MFMA16(ap, ones, lacc[i], 0, 0, 0);
        oacc[i][0] = MFMA16(ap, bv0, oacc[i][0], 0, 0, 0);
        oacc[i][1] = MFMA16(ap, bv1, oacc[i][1], 0, 0, 0);
        oacc[i][2] = MFMA16(ap, bv2, oacc[i][2], 0, 0, 0);
        oacc[i][3] = MFMA16(ap, bv3, oacc[i][3], 0, 0, 0);
        __builtin_amdgcn_s_setprio(0);
      }
    }
  };

  for (int t = lo; t <= hi; t += 2) {
    if (t + 1 <= hi) loadK((t + 1) << 6, kb2);
    tilec(t << 6, ka);
    if (t + 1 <= hi) {
      if (t + 2 <= hi) loadK((t + 2) << 6, ka);
      tilec((t + 1) << 6, kb2);
    }
  }

  // ---- epilogue: O/l -> bf16 [B,S,H*64], granule-swizzled for GEMM3 staging ----
  const int b = bh >> 4, h = bh & 15;
  #pragma unroll
  for (int i = 0; i < 4; ++i) {
    #pragma unroll
    for (int r = 0; r < 4; ++r) {
      float inv = 1.f / lacc[i][r];
      int srow = t0 + i * 16 + quad * 4 + r;
      size_t rowoff = ((size_t)(b * 4096 + srow)) * 1024 + h * 64;
      #pragma unroll
      for (int jd = 0; jd < 4; ++jd) {
        int g = ((jd * 2 + (l16 >> 3)) ^ srow) & 7;
        ob[rowoff + (g << 3) + (l16 & 7)] = f2bf(oacc[i][jd][r] * inv);
      }
    }
  }
}

// ---------------- launch ----------------

extern "C" void kernel_launch(void* const* d_in, const int* in_sizes, int n_in,
                              void* d_out, int out_size, void* d_ws, size_t ws_size,
                              hipStream_t stream) {
  const float* x    = (const float*)d_in[0];
  const float* wqkv = (const float*)d_in[1];
  const float* wout = (const float*)d_in[2];
  float* out = (float*)d_out;

  u16* ws    = (u16*)d_ws;
  u16* xb    = ws;                                   // 8192*1024  (reused as obuf)
  u16* wqkvb = xb + (size_t)8192 * 1024;             // 3072*1024
  u16* woutb = wqkvb + (size_t)3072 * 1024;          // 1024*1024
  u16* qbuf  = woutb + (size_t)1024 * 1024;          // [2,16,4096,64]
  u16* kbuf  = qbuf + (size_t)8388608;
  u16* vbuf  = kbuf + (size_t)8388608;               // (unused now)
  u16* vtb   = vbuf + (size_t)8388608;               // operand-order V (written by gemm1)
  u16* obuf  = xb;                                   // alias: xb dead after gemm1

  cast_all_kernel<<<12288, 256, 0, stream>>>(x, wqkv, wout, ws);

  gemm_bt<1><<<dim3(24, 64), 256, 0, stream>>>(xb, wqkvb, nullptr, qbuf, kbuf, vtb,
                                               8192, 3072, 1024);
  attn_kernel<<<512, 256, 0, stream>>>(qbuf, kbuf, vtb, obuf);
  gemm_bt<0><<<dim3(8, 64), 256, 0, stream>>>(obuf, woutb, out, nullptr, nullptr, nullptr,
                                              8192, 1024, 1024);
}